// Round 19
// baseline (136.139 us; speedup 1.0000x reference)
//
#include <hip/hip_runtime.h>
#include <hip/hip_bf16.h>

// RGCN: N=4096, D=128, R=8, B=8, two layers + LN(+ReLU).
// R19: R18 base + counted-vmcnt barriers in agg32 (T3/T4): per phase,
// s_waitcnt vmcnt(4) + raw s_barrier keeps the 4 raw A-loads in flight
// across the barrier while guaranteeing each wave's gll (B-panel) writes
// completed. Order pinned with sched_barrier(0). Everything else = R18.

#define NN 4096
#define DD 128

typedef __attribute__((ext_vector_type(8)))  short    s16x8;
typedef __attribute__((ext_vector_type(4)))  short    s16x4;
typedef __attribute__((ext_vector_type(8)))  __bf16   bf16v8;
typedef __attribute__((ext_vector_type(4)))  float    f32x4;
typedef __attribute__((ext_vector_type(16))) float    f32x16;
typedef __attribute__((ext_vector_type(4)))  int      i32x4;
typedef __attribute__((ext_vector_type(4)))  unsigned u32x4;

__device__ inline short f2bf(float f) {            // f32 -> bf16 bits, RNE
  union { float f; unsigned u; } v; v.f = f;
  unsigned r = (v.u + 0x7FFFu + ((v.u >> 16) & 1u)) >> 16;
  return (short)r;
}
__device__ inline unsigned u2bf2(unsigned ulo, unsigned uhi) { // 2 f32 bits -> packed bf16x2
  unsigned lo = (ulo + 0x7FFFu + ((ulo >> 16) & 1u)) >> 16;
  unsigned hi = (uhi + 0x7FFFu + ((uhi >> 16) & 1u)) & 0xFFFF0000u;
  return lo | hi;
}
__device__ inline float bf2f(short h) {
  union { unsigned u; float f; } v; v.u = ((unsigned)(unsigned short)h) << 16;
  return v.f;
}

__device__ inline f32x4 mfma16(s16x8 a, s16x8 b, f32x4 c) {
  return __builtin_amdgcn_mfma_f32_16x16x32_bf16(
      __builtin_bit_cast(bf16v8, a), __builtin_bit_cast(bf16v8, b), c, 0, 0, 0);
}
__device__ inline f32x16 mfma32(s16x8 a, s16x8 b, f32x16 c) {
  return __builtin_amdgcn_mfma_f32_32x32x16_bf16(
      __builtin_bit_cast(bf16v8, a), __builtin_bit_cast(bf16v8, b), c, 0, 0, 0);
}

// byte-pair -> halfword mask via v_perm + (x<<8)-x
__device__ inline unsigned pairmask(unsigned q, unsigned sel) {
  unsigned s = __builtin_amdgcn_perm(0u, q, sel);
  return (s << 8) - s;
}

// async global -> LDS, 16B per lane. LDS dest wave-uniform base; src per-lane.
__device__ inline void gll16(const void* gsrc, void* ldst) {
  __builtin_amdgcn_global_load_lds(
      (const __attribute__((address_space(1))) unsigned*)gsrc,
      (__attribute__((address_space(3))) unsigned*)ldst, 16, 0, 0);
}

// ---------------------------------------------------------------------------
// K1: w_r = sum_b weights[r,b]*bases[b] (r==8 -> W_self), 16x16 B-frag order.
// ---------------------------------------------------------------------------
__global__ void prep_w(const float* __restrict__ b1, const float* __restrict__ w1,
                       const float* __restrict__ ws1,
                       const float* __restrict__ b2, const float* __restrict__ w2,
                       const float* __restrict__ ws2,
                       short* __restrict__ wfrag) {
  int tid = blockIdx.x * 256 + threadIdx.x;
  int layer = (tid >= 18432);
  int t0 = tid - layer * 18432;
  int lane = t0 & 63;
  int t = (t0 >> 6) & 7;
  int s = (t0 >> 9) & 3;
  int r = t0 >> 11;
  const float* bases = layer ? b2 : b1;
  const float* wts   = layer ? w2 : w1;
  const float* wself = layer ? ws2 : ws1;
  int o  = t * 16 + (lane & 15);
  int i0 = s * 32 + 8 * (lane >> 4);
  short v[8];
#pragma unroll
  for (int e = 0; e < 8; ++e) {
    int i = i0 + e;
    float a;
    if (r < 8) {
      a = 0.f;
#pragma unroll
      for (int b = 0; b < 8; ++b)
        a += wts[r * 8 + b] * bases[((size_t)b * 128 + i) * 128 + o];
    } else {
      a = wself[(size_t)i * 128 + o];
    }
    v[e] = f2bf(a);
  }
  *(s16x8*)(wfrag + (size_t)tid * 8) = *(s16x8*)v;
}

// ---------------------------------------------------------------------------
// K2: xw_r = xin @ w_r (16x16 MFMA). LAYOUT=1 writes 32x32 agg B-frags:
// [r][ks(256)][ct(4)][lane][e(8)]. LAYOUT=0 = R9 16x16 frags.
// r==8: hacc = xin @ W_self + bias.
// ---------------------------------------------------------------------------
template <int LAYOUT>
__global__ void xw_gemm(const float* __restrict__ xin, const short* __restrict__ wfrag,
                        short* __restrict__ xwfrag, float* __restrict__ hacc,
                        const float* __restrict__ bias) {
  __shared__ short lds[4][32 * 128];
  int w = threadIdx.x >> 6, lane = threadIdx.x & 63;
  int widx = blockIdx.x * 4 + w;
  int m = widx & 127;
  int r = widx >> 7;
  int l15 = lane & 15, l4 = lane >> 4;

  f32x4 acc[2][8] = {};

#pragma unroll
  for (int s = 0; s < 4; ++s) {
    s16x8 A[2];
#pragma unroll
    for (int nt = 0; nt < 2; ++nt) {
      const float* xp = xin + (size_t)(m * 32 + nt * 16 + l15) * 128 + s * 32 + 8 * l4;
      f32x4 f0 = *(const f32x4*)xp;
      f32x4 f1 = *(const f32x4*)(xp + 4);
      s16x8 av;
#pragma unroll
      for (int e = 0; e < 4; ++e) av[e] = f2bf(f0[e]);
#pragma unroll
      for (int e = 0; e < 4; ++e) av[4 + e] = f2bf(f1[e]);
      A[nt] = av;
    }
    const short* bp = wfrag + ((size_t)(r * 4 + s) * 8) * 512 + lane * 8;
#pragma unroll
    for (int t = 0; t < 8; ++t) {
      s16x8 B = *(const s16x8*)(bp + t * 512);
      acc[0][t] = mfma16(A[0], B, acc[0][t]);
      acc[1][t] = mfma16(A[1], B, acc[1][t]);
    }
  }

  if (r == 8) {
#pragma unroll
    for (int nt = 0; nt < 2; ++nt)
#pragma unroll
      for (int t = 0; t < 8; ++t)
#pragma unroll
        for (int j = 0; j < 4; ++j) {
          int row = m * 32 + nt * 16 + 4 * l4 + j;
          int col = t * 16 + l15;
          hacc[(size_t)row * 128 + col] = acc[nt][t][j] + bias[col];
        }
  } else {
#pragma unroll
    for (int nt = 0; nt < 2; ++nt)
#pragma unroll
      for (int t = 0; t < 8; ++t)
#pragma unroll
        for (int j = 0; j < 4; ++j)
          lds[w][(nt * 16 + 4 * l4 + j) * 128 + t * 16 + l15] = f2bf(acc[nt][t][j]);
    __syncthreads();
    if (LAYOUT == 1) {
      int l31 = lane & 31, h = lane >> 5;
#pragma unroll
      for (int s = 0; s < 2; ++s)
#pragma unroll
        for (int ct = 0; ct < 4; ++ct) {
          short v[8];
#pragma unroll
          for (int e = 0; e < 8; ++e)
            v[e] = lds[w][(s * 16 + 8 * h + e) * 128 + ct * 32 + l31];
          *(s16x8*)(xwfrag + (((size_t)(r * 256 + m * 2 + s) * 4 + ct) * 64 + lane) * 8)
              = *(s16x8*)v;
        }
    } else {
#pragma unroll
      for (int t = 0; t < 8; ++t) {
        short v[8];
#pragma unroll
        for (int e = 0; e < 8; ++e) v[e] = lds[w][(8 * l4 + e) * 128 + t * 16 + l15];
        *(s16x8*)(xwfrag + ((size_t)(r * 128 + m) * 8 + t) * 512 + lane * 8) = *(s16x8*)v;
      }
    }
  }
}

// ---------------------------------------------------------------------------
// K3: 32x32x16 aggregation, raw inputs, one phase per ks, counted-vmcnt
// barriers. Grid (32 kc, 16 rowblk), block 512 = 8 waves; wave = 32 rows x
// 128 cols, acc = 4 x f32x16.
// Phase: {4x gll stage(next panel)} [sched_barrier] {conv A(ks)} {4x raw
// ldraw(ks+1)} {setprio(1) MFMA cluster setprio(0)} {vmcnt(4) + s_barrier}.
// vmcnt(4): each wave's gll (older than its 4 raw loads) complete at the
// barrier -> all waves' panel writes done; raw A stays in flight.
// ---------------------------------------------------------------------------
__launch_bounds__(512, 4)
__global__ void agg32(const float* __restrict__ adj, const int* __restrict__ et,
                      const short* __restrict__ xw32, short* __restrict__ partial) {
  int tid = threadIdx.x;
  int w = tid >> 6, lane = tid & 63;
  int kc = blockIdx.x, rowblk = blockIdx.y;

  __shared__ short bpanel[2][16384];           // 2 x 32KB

  f32x16 acc[4] = {};

  int rt = rowblk * 8 + w;
  int row = rt * 32 + (lane & 31);
  int h   = lane >> 5;
  const float* apf = adj + (size_t)row * 4096 + kc * 128 + 8 * h;
  const int*   epf = et  + (size_t)row * 4096 + kc * 128 + 8 * h;

  // stage full 32KB panel for ks into bpanel[buf] (4 gll/wave, 1KB each)
  auto stage = [&](int buf, int ks) {
#pragma unroll
    for (int i = 0; i < 4; ++i) {
      int base = i * 512 + w * 64;
      int rl   = base >> 8;                    // uniform per (i, wave)
      int rem  = (base & 255) + lane;
      const short* src = xw32 + ((size_t)(rl * 256 + kc * 8 + ks)) * 2048 + rem * 8;
      gll16(src, &bpanel[buf][(size_t)base * 8]);
    }
  };

  u32x4 Fa, Fb, Ea, Eb;                        // single raw slot (depth 1)
  struct Cv { u32x4 av; unsigned o0, o1; } C;
  auto ldraw = [&](int ks) {
    Fa = *(const u32x4*)(apf + ks * 16);
    Fb = *(const u32x4*)(apf + ks * 16 + 4);
    Ea = *(const u32x4*)(epf + ks * 16);
    Eb = *(const u32x4*)(epf + ks * 16 + 4);
  };
  auto conv = [&]() {
    C.av[0] = u2bf2(Fa[0], Fa[1]); C.av[1] = u2bf2(Fa[2], Fa[3]);
    C.av[2] = u2bf2(Fb[0], Fb[1]); C.av[3] = u2bf2(Fb[2], Fb[3]);
    unsigned o0 = 0, o1 = 0;
#pragma unroll
    for (int j = 0; j < 4; ++j) o0 |= (1u << (Ea[j] & 7u)) << (8 * j);
#pragma unroll
    for (int j = 0; j < 4; ++j) o1 |= (1u << (Eb[j] & 7u)) << (8 * j);
    C.o0 = o0; C.o1 = o1;
  };

  // prologue: stage panel0, load raw ks0, full drain
  stage(0, 0);
  ldraw(0);
  __syncthreads();                              // panel0 + raw0 complete

  int buf = 0;
#pragma unroll
  for (int ks = 0; ks < 8; ++ks) {
    if (ks < 7) {
      stage(buf ^ 1, ks + 1);                   // 4x gll: B for next phase
      __builtin_amdgcn_sched_barrier(0);        // pin gll before raw loads
    }
    conv();                                     // raw slot holds ks
    if (ks < 7)
      ldraw(ks + 1);                            // 4x raw: A for next phase
    u32x4 av = C.av;
    unsigned o0 = C.o0, o1 = C.o1;

    __builtin_amdgcn_s_setprio(1);
#pragma unroll
    for (int r = 0; r < 8; ++r) {
      unsigned q0 = (o0 >> r) & 0x01010101u;
      unsigned q1 = (o1 >> r) & 0x01010101u;
      unsigned m0 = pairmask(q0, 0x01010000u);
      unsigned m1 = pairmask(q0, 0x03030202u);
      unsigned m2 = pairmask(q1, 0x01010000u);
      unsigned m3 = pairmask(q1, 0x03030202u);
      u32x4 mv;
      mv[0] = av[0] & m0; mv[1] = av[1] & m1;
      mv[2] = av[2] & m2; mv[3] = av[3] & m3;
      s16x8 mf = __builtin_bit_cast(s16x8, mv);
#pragma unroll
      for (int ct = 0; ct < 4; ++ct) {
        s16x8 b = *(const s16x8*)&bpanel[buf][((r * 4 + ct) * 64 + lane) * 8];
        acc[ct] = mfma32(mf, b, acc[ct]);
      }
    }
    __builtin_amdgcn_s_setprio(0);
    if (ks < 7) {
      // counted barrier: this wave's 4 gll (older than its 4 raw) complete;
      // raw A-loads stay in flight across the barrier.
      asm volatile("s_waitcnt vmcnt(4)" ::: "memory");
      __builtin_amdgcn_s_barrier();
      __builtin_amdgcn_sched_barrier(0);        // no ds_read hoisting above
    }
    buf ^= 1;
  }

  // epilogue: bf16 partials, 8B lane-contiguous stores
  short* tile = partial + ((size_t)(kc * 16 + rowblk)) * 32768;
#pragma unroll
  for (int ct = 0; ct < 4; ++ct)
#pragma unroll
    for (int rq = 0; rq < 4; ++rq) {
      short v[4];
#pragma unroll
      for (int j = 0; j < 4; ++j) v[j] = f2bf(acc[ct][rq * 4 + j]);
      __builtin_nontemporal_store(
          *(s16x4*)v, (s16x4*)(tile + ((size_t)((w * 4 + ct) * 4 + rq) * 64 + lane) * 4));
    }
}

// ---------------------------------------------------------------------------
// K4: out = LN( hacc + sum_kc bf16-partial ) (+ReLU).
// ---------------------------------------------------------------------------
__global__ void reduce_ln32(const short* __restrict__ partial,
                            const float* __restrict__ hacc,
                            const float* __restrict__ gamma, const float* __restrict__ beta,
                            float* __restrict__ out, int relu) {
  int lane = threadIdx.x & 63;
  int g = blockIdx.x * 4 + (threadIdx.x >> 6);   // row-quad id, 0..1023
  int rowbase = g * 4;
  int rb   = rowbase >> 8;
  int w    = (rowbase >> 5) & 7;
  int rq   = (rowbase >> 3) & 3;
  int bit2 = (rowbase >> 2) & 1;
  int l31 = lane & 31;
  int ct0 = lane >> 5;
  int lsrc = l31 + 32 * bit2;
  int c0 = lane, c1 = lane + 64;

  f32x4 v0, v1;
#pragma unroll
  for (int j = 0; j < 4; ++j) {
    v0[j] = hacc[(size_t)(rowbase + j) * 128 + c0];
    v1[j] = hacc[(size_t)(rowbase + j) * 128 + c1];
  }
  size_t off0 = ((size_t)((w * 4 + ct0) * 4 + rq) * 64 + lsrc) * 4;
  size_t off1 = ((size_t)((w * 4 + ct0 + 2) * 4 + rq) * 64 + lsrc) * 4;
  for (int kc = 0; kc < 32; ++kc) {
    const short* tile = partial + ((size_t)(kc * 16 + rb)) * 32768;
    s16x4 p0 = *(const s16x4*)(tile + off0);
    s16x4 p1 = *(const s16x4*)(tile + off1);
#pragma unroll
    for (int j = 0; j < 4; ++j) { v0[j] += bf2f(p0[j]); v1[j] += bf2f(p1[j]); }
  }

  f32x4 s, sq;
#pragma unroll
  for (int j = 0; j < 4; ++j) {
    s[j]  = v0[j] + v1[j];
    sq[j] = v0[j] * v0[j] + v1[j] * v1[j];
  }
#pragma unroll
  for (int off = 32; off; off >>= 1) {
#pragma unroll
    for (int j = 0; j < 4; ++j) {
      s[j]  += __shfl_xor(s[j],  off);
      sq[j] += __shfl_xor(sq[j], off);
    }
  }
  float g0 = gamma[c0], g1 = gamma[c1], b0 = beta[c0], b1 = beta[c1];
#pragma unroll
  for (int j = 0; j < 4; ++j) {
    float mu  = s[j] * (1.f / 128.f);
    float var = sq[j] * (1.f / 128.f) - mu * mu;
    float inv = rsqrtf(var + 1e-5f);
    float y0 = (v0[j] - mu) * inv * g0 + b0;
    float y1 = (v1[j] - mu) * inv * g1 + b1;
    if (relu) { y0 = fmaxf(y0, 0.f); y1 = fmaxf(y1, 0.f); }
    out[(size_t)(rowbase + j) * 128 + c0] = y0;
    out[(size_t)(rowbase + j) * 128 + c1] = y1;
  }
}

// ---------------------------------------------------------------------------
// Fallback path (R9-proven): 16x16 agg from raw inputs with f32 partials.
// ---------------------------------------------------------------------------
__launch_bounds__(512, 4)
__global__ void agg_fb(const float* __restrict__ adj, const int* __restrict__ et,
                       const short* __restrict__ xwfrag, float* __restrict__ partial,
                       int msteps) {
  int tid = threadIdx.x;
  int w = tid >> 6, lane = tid & 63;
  int kc = blockIdx.x, rowblk = blockIdx.y;
  int l15 = lane & 15, l4 = lane >> 4;
  int row = rowblk * 128 + w * 16 + l15;

  f32x4 acc[8] = {};
  for (int ms = 0; ms < msteps; ++ms) {
    int gm = kc * msteps + ms;
    size_t rbase = (size_t)row * 4096 + gm * 32 + 8 * l4;
    f32x4 f0 = *(const f32x4*)(adj + rbase);
    f32x4 f1 = *(const f32x4*)(adj + rbase + 4);
    i32x4 e0 = *(const i32x4*)(et + rbase);
    i32x4 e1 = *(const i32x4*)(et + rbase + 4);
    s16x8 a, cd;
#pragma unroll
    for (int e = 0; e < 4; ++e) { a[e] = f2bf(f0[e]); cd[e] = (short)e0[e]; }
#pragma unroll
    for (int e = 0; e < 4; ++e) { a[4 + e] = f2bf(f1[e]); cd[4 + e] = (short)e1[e]; }
#pragma unroll
    for (int r = 0; r < 8; ++r) {
      const short* bp = xwfrag + ((size_t)(r * 128 + gm) * 8) * 512 + lane * 8;
      s16x8 mf;
#pragma unroll
      for (int e = 0; e < 8; ++e) mf[e] = (cd[e] == (short)r) ? a[e] : (short)0;
#pragma unroll
      for (int t = 0; t < 8; ++t) {
        s16x8 b = *(const s16x8*)(bp + t * 512);
        acc[t] = mfma16(mf, b, acc[t]);
      }
    }
  }
  float* tile = partial + ((size_t)kc * 32 + rowblk) * 16384;
#pragma unroll
  for (int t = 0; t < 8; ++t)
    __builtin_nontemporal_store(
        acc[t], (f32x4*)(tile + (size_t)((w * 8 + t) * 256 + lane * 4)));
}

__global__ void reduce_fb(const float* __restrict__ partial, int KC,
                          const float* __restrict__ hacc,
                          const float* __restrict__ gamma, const float* __restrict__ beta,
                          float* __restrict__ out, int relu) {
  int lane = threadIdx.x & 63;
  int g = blockIdx.x * 4 + (threadIdx.x >> 6);
  int rowblk = g >> 5;
  int q = g & 31;
  int wq  = q >> 2;
  int l4g = q & 3;
  int rowbase = rowblk * 128 + q * 4;
  int c0 = lane, c1 = lane + 64;
  int t0 = lane >> 4, li = lane & 15;
  f32x4 v0, v1;
#pragma unroll
  for (int j = 0; j < 4; ++j) {
    v0[j] = hacc[(size_t)(rowbase + j) * 128 + c0];
    v1[j] = hacc[(size_t)(rowbase + j) * 128 + c1];
  }
  size_t off0 = (size_t)((wq * 8 + t0) * 256) + (l4g * 16 + li) * 4;
  size_t off1 = (size_t)((wq * 8 + t0 + 4) * 256) + (l4g * 16 + li) * 4;
  for (int kc = 0; kc < KC; ++kc) {
    const float* tile = partial + ((size_t)kc * 32 + rowblk) * 16384;
    f32x4 p0 = *(const f32x4*)(tile + off0);
    f32x4 p1 = *(const f32x4*)(tile + off1);
#pragma unroll
    for (int j = 0; j < 4; ++j) { v0[j] += p0[j]; v1[j] += p1[j]; }
  }
  f32x4 s, sq;
#pragma unroll
  for (int j = 0; j < 4; ++j) {
    s[j]  = v0[j] + v1[j];
    sq[j] = v0[j] * v0[j] + v1[j] * v1[j];
  }
#pragma unroll
  for (int off = 32; off; off >>= 1) {
#pragma unroll
    for (int j = 0; j < 4; ++j) {
      s[j]  += __shfl_xor(s[j],  off);
      sq[j] += __shfl_xor(sq[j], off);
    }
  }
  float g0 = gamma[c0], g1 = gamma[c1], b0 = beta[c0], b1 = beta[c1];
#pragma unroll
  for (int j = 0; j < 4; ++j) {
    float mu  = s[j] * (1.f / 128.f);
    float var = sq[j] * (1.f / 128.f) - mu * mu;
    float inv = rsqrtf(var + 1e-5f);
    float y0 = (v0[j] - mu) * inv * g0 + b0;
    float y1 = (v1[j] - mu) * inv * g1 + b1;
    if (relu) { y0 = fmaxf(y0, 0.f); y1 = fmaxf(y1, 0.f); }
    out[(size_t)(rowbase + j) * 128 + c0] = y0;
    out[(size_t)(rowbase + j) * 128 + c1] = y1;
  }
}

// ---------------------------------------------------------------------------
extern "C" void kernel_launch(void* const* d_in, const int* in_sizes, int n_in,
                              void* d_out, int out_size, void* d_ws, size_t ws_size,
                              hipStream_t stream) {
  const float* x      = (const float*)d_in[0];
  const float* adj    = (const float*)d_in[1];
  const int*   et     = (const int*)d_in[2];
  const float* bases1 = (const float*)d_in[3];
  const float* wts1   = (const float*)d_in[4];
  const float* wself1 = (const float*)d_in[5];
  const float* bself1 = (const float*)d_in[6];
  const float* bases2 = (const float*)d_in[7];
  const float* wts2   = (const float*)d_in[8];
  const float* wself2 = (const float*)d_in[9];
  const float* bself2 = (const float*)d_in[10];
  const float* gamma1 = (const float*)d_in[11];
  const float* beta1  = (const float*)d_in[12];
  const float* gamma2 = (const float*)d_in[13];
  const float* beta2  = (const float*)d_in[14];

  char* ws = (char*)d_ws;
  const size_t BASE = 589824ull + 8388608ull + 2097152ull + 2097152ull; // 13,172,736
  short* wfrag  = (short*)(ws);
  short* xwfrag = (short*)(ws + 589824);
  float* hacc   = (float*)(ws + 589824 + 8388608);
  float* h1     = (float*)(ws + 589824 + 8388608 + 2097152);

  const size_t P16 = 33554432ull;                 // bf16 partials
  bool main_path = ws_size >= BASE + P16;         // 46.7 MB

  prep_w<<<144, 256, 0, stream>>>(bases1, wts1, wself1, bases2, wts2, wself2, wfrag);

  if (main_path) {
    short* partial16 = (short*)(ws + BASE);
    dim3 agrid(32, 16);
    // layer 1
    xw_gemm<1><<<288, 256, 0, stream>>>(x, wfrag, xwfrag, hacc, bself1);
    agg32<<<agrid, 512, 0, stream>>>(adj, et, xwfrag, partial16);
    reduce_ln32<<<256, 256, 0, stream>>>(partial16, hacc, gamma1, beta1, h1, 1);
    // layer 2
    xw_gemm<1><<<288, 256, 0, stream>>>(h1, wfrag + 147456, xwfrag, hacc, bself2);
    agg32<<<agrid, 512, 0, stream>>>(adj, et, xwfrag, partial16);
    reduce_ln32<<<256, 256, 0, stream>>>(partial16, hacc, gamma2, beta2, (float*)d_out, 0);
  } else {
    // fallback: f32 partials, raw-input 16x16 agg
    int KC = 0;
    const int utiers[5] = {16, 8, 4, 2, 1};
    for (int i = 0; i < 5 && !KC; ++i)
      if (ws_size >= BASE + (size_t)utiers[i] * 2097152ull) KC = utiers[i];
    if (!KC) KC = 1;
    float* partialf = (float*)(ws + BASE);
    int msteps = 128 / KC;
    dim3 agrid(KC, 32);

    xw_gemm<0><<<288, 256, 0, stream>>>(x, wfrag, xwfrag, hacc, bself1);
    agg_fb<<<agrid, 512, 0, stream>>>(adj, et, xwfrag, partialf, msteps);
    reduce_fb<<<256, 256, 0, stream>>>(partialf, KC, hacc, gamma1, beta1, h1, 1);

    xw_gemm<0><<<288, 256, 0, stream>>>(h1, wfrag + 147456, xwfrag, hacc, bself2);
    agg_fb<<<agrid, 512, 0, stream>>>(adj, et, xwfrag, partialf, msteps);
    reduce_fb<<<256, 256, 0, stream>>>(partialf, KC, hacc, gamma2, beta2, (float*)d_out, 0);
  }
}

// Round 20
// 131.824 us; speedup vs baseline: 1.0327x; 1.0327x over previous
//
#include <hip/hip_runtime.h>
#include <hip/hip_bf16.h>

// RGCN: N=4096, D=128, R=8, B=8, two layers + LN(+ReLU).
// R20 = R18 (best measured: 132.8us), resubmitted verbatim after R19's
// counted-vmcnt experiment came back neutral. agg reads raw adj/et (no pack
// kernel), one phase per ks, B panel via global_load_lds (2x32KB dbuf),
// setprio-wrapped MFMA cluster, 32x32x16 MFMA, SWAR one-hot masking,
// bf16 partials, fused reduce+LN.

#define NN 4096
#define DD 128

typedef __attribute__((ext_vector_type(8)))  short    s16x8;
typedef __attribute__((ext_vector_type(4)))  short    s16x4;
typedef __attribute__((ext_vector_type(8)))  __bf16   bf16v8;
typedef __attribute__((ext_vector_type(4)))  float    f32x4;
typedef __attribute__((ext_vector_type(16))) float    f32x16;
typedef __attribute__((ext_vector_type(4)))  int      i32x4;
typedef __attribute__((ext_vector_type(4)))  unsigned u32x4;

__device__ inline short f2bf(float f) {            // f32 -> bf16 bits, RNE
  union { float f; unsigned u; } v; v.f = f;
  unsigned r = (v.u + 0x7FFFu + ((v.u >> 16) & 1u)) >> 16;
  return (short)r;
}
__device__ inline unsigned u2bf2(unsigned ulo, unsigned uhi) { // 2 f32 bits -> packed bf16x2
  unsigned lo = (ulo + 0x7FFFu + ((ulo >> 16) & 1u)) >> 16;
  unsigned hi = (uhi + 0x7FFFu + ((uhi >> 16) & 1u)) & 0xFFFF0000u;
  return lo | hi;
}
__device__ inline float bf2f(short h) {
  union { unsigned u; float f; } v; v.u = ((unsigned)(unsigned short)h) << 16;
  return v.f;
}

__device__ inline f32x4 mfma16(s16x8 a, s16x8 b, f32x4 c) {
  return __builtin_amdgcn_mfma_f32_16x16x32_bf16(
      __builtin_bit_cast(bf16v8, a), __builtin_bit_cast(bf16v8, b), c, 0, 0, 0);
}
__device__ inline f32x16 mfma32(s16x8 a, s16x8 b, f32x16 c) {
  return __builtin_amdgcn_mfma_f32_32x32x16_bf16(
      __builtin_bit_cast(bf16v8, a), __builtin_bit_cast(bf16v8, b), c, 0, 0, 0);
}

// byte-pair -> halfword mask via v_perm + (x<<8)-x
__device__ inline unsigned pairmask(unsigned q, unsigned sel) {
  unsigned s = __builtin_amdgcn_perm(0u, q, sel);
  return (s << 8) - s;
}

// async global -> LDS, 16B per lane. LDS dest wave-uniform base; src per-lane.
__device__ inline void gll16(const void* gsrc, void* ldst) {
  __builtin_amdgcn_global_load_lds(
      (const __attribute__((address_space(1))) unsigned*)gsrc,
      (__attribute__((address_space(3))) unsigned*)ldst, 16, 0, 0);
}

// ---------------------------------------------------------------------------
// K1: w_r = sum_b weights[r,b]*bases[b] (r==8 -> W_self), 16x16 B-frag order
// (consumed only by xw_gemm): [layer][r(9)][s(4)][t(8)][lane][e(8)],
// elem = w[i = 32s+8*(l>>4)+e][o = 16t+(l&15)].
// ---------------------------------------------------------------------------
__global__ void prep_w(const float* __restrict__ b1, const float* __restrict__ w1,
                       const float* __restrict__ ws1,
                       const float* __restrict__ b2, const float* __restrict__ w2,
                       const float* __restrict__ ws2,
                       short* __restrict__ wfrag) {
  int tid = blockIdx.x * 256 + threadIdx.x;
  int layer = (tid >= 18432);
  int t0 = tid - layer * 18432;
  int lane = t0 & 63;
  int t = (t0 >> 6) & 7;
  int s = (t0 >> 9) & 3;
  int r = t0 >> 11;
  const float* bases = layer ? b2 : b1;
  const float* wts   = layer ? w2 : w1;
  const float* wself = layer ? ws2 : ws1;
  int o  = t * 16 + (lane & 15);
  int i0 = s * 32 + 8 * (lane >> 4);
  short v[8];
#pragma unroll
  for (int e = 0; e < 8; ++e) {
    int i = i0 + e;
    float a;
    if (r < 8) {
      a = 0.f;
#pragma unroll
      for (int b = 0; b < 8; ++b)
        a += wts[r * 8 + b] * bases[((size_t)b * 128 + i) * 128 + o];
    } else {
      a = wself[(size_t)i * 128 + o];
    }
    v[e] = f2bf(a);
  }
  *(s16x8*)(wfrag + (size_t)tid * 8) = *(s16x8*)v;
}

// ---------------------------------------------------------------------------
// K2: xw_r = xin @ w_r (16x16 MFMA). LAYOUT=1 writes 32x32 agg B-frags:
// [r][ks(256)][ct(4)][lane][e(8)], elem = xw[k][c],
//   k = ks*16 + 8*(l>>5)+e, c = ct*32 + (l&31).
// LAYOUT=0 writes R9 16x16 frags. r==8: hacc = xin @ W_self + bias.
// ---------------------------------------------------------------------------
template <int LAYOUT>
__global__ void xw_gemm(const float* __restrict__ xin, const short* __restrict__ wfrag,
                        short* __restrict__ xwfrag, float* __restrict__ hacc,
                        const float* __restrict__ bias) {
  __shared__ short lds[4][32 * 128];
  int w = threadIdx.x >> 6, lane = threadIdx.x & 63;
  int widx = blockIdx.x * 4 + w;
  int m = widx & 127;
  int r = widx >> 7;
  int l15 = lane & 15, l4 = lane >> 4;

  f32x4 acc[2][8] = {};

#pragma unroll
  for (int s = 0; s < 4; ++s) {
    s16x8 A[2];
#pragma unroll
    for (int nt = 0; nt < 2; ++nt) {
      const float* xp = xin + (size_t)(m * 32 + nt * 16 + l15) * 128 + s * 32 + 8 * l4;
      f32x4 f0 = *(const f32x4*)xp;
      f32x4 f1 = *(const f32x4*)(xp + 4);
      s16x8 av;
#pragma unroll
      for (int e = 0; e < 4; ++e) av[e] = f2bf(f0[e]);
#pragma unroll
      for (int e = 0; e < 4; ++e) av[4 + e] = f2bf(f1[e]);
      A[nt] = av;
    }
    const short* bp = wfrag + ((size_t)(r * 4 + s) * 8) * 512 + lane * 8;
#pragma unroll
    for (int t = 0; t < 8; ++t) {
      s16x8 B = *(const s16x8*)(bp + t * 512);
      acc[0][t] = mfma16(A[0], B, acc[0][t]);
      acc[1][t] = mfma16(A[1], B, acc[1][t]);
    }
  }

  if (r == 8) {
#pragma unroll
    for (int nt = 0; nt < 2; ++nt)
#pragma unroll
      for (int t = 0; t < 8; ++t)
#pragma unroll
        for (int j = 0; j < 4; ++j) {
          int row = m * 32 + nt * 16 + 4 * l4 + j;
          int col = t * 16 + l15;
          hacc[(size_t)row * 128 + col] = acc[nt][t][j] + bias[col];
        }
  } else {
#pragma unroll
    for (int nt = 0; nt < 2; ++nt)
#pragma unroll
      for (int t = 0; t < 8; ++t)
#pragma unroll
        for (int j = 0; j < 4; ++j)
          lds[w][(nt * 16 + 4 * l4 + j) * 128 + t * 16 + l15] = f2bf(acc[nt][t][j]);
    __syncthreads();
    if (LAYOUT == 1) {
      int l31 = lane & 31, h = lane >> 5;
#pragma unroll
      for (int s = 0; s < 2; ++s)
#pragma unroll
        for (int ct = 0; ct < 4; ++ct) {
          short v[8];
#pragma unroll
          for (int e = 0; e < 8; ++e)
            v[e] = lds[w][(s * 16 + 8 * h + e) * 128 + ct * 32 + l31];
          *(s16x8*)(xwfrag + (((size_t)(r * 256 + m * 2 + s) * 4 + ct) * 64 + lane) * 8)
              = *(s16x8*)v;
        }
    } else {
#pragma unroll
      for (int t = 0; t < 8; ++t) {
        short v[8];
#pragma unroll
        for (int e = 0; e < 8; ++e) v[e] = lds[w][(8 * l4 + e) * 128 + t * 16 + l15];
        *(s16x8*)(xwfrag + ((size_t)(r * 128 + m) * 8 + t) * 512 + lane * 8) = *(s16x8*)v;
      }
    }
  }
}

// ---------------------------------------------------------------------------
// K3: 32x32x16 aggregation, raw inputs, one phase per ks (R14/R18 structure).
// Grid (32 kc, 16 rowblk), block 512 = 8 waves; wave = 32 rows x 128 cols,
// acc = 4 x f32x16. Per phase: issue async B-panel stage FIRST (gll,
// 32KB dbuf), then convert A (raw loaded last phase), then prefetch next
// raw A, then setprio(1)-wrapped MFMA cluster, barrier. 8 barriers.
// ---------------------------------------------------------------------------
__launch_bounds__(512, 4)
__global__ void agg32(const float* __restrict__ adj, const int* __restrict__ et,
                      const short* __restrict__ xw32, short* __restrict__ partial) {
  int tid = threadIdx.x;
  int w = tid >> 6, lane = tid & 63;
  int kc = blockIdx.x, rowblk = blockIdx.y;

  __shared__ short bpanel[2][16384];           // 2 x 32KB

  f32x16 acc[4] = {};

  int rt = rowblk * 8 + w;
  int row = rt * 32 + (lane & 31);
  int h   = lane >> 5;
  const float* apf = adj + (size_t)row * 4096 + kc * 128 + 8 * h;
  const int*   epf = et  + (size_t)row * 4096 + kc * 128 + 8 * h;

  // stage full 32KB panel for ks into bpanel[buf] (4 gll/wave, 1KB each)
  auto stage = [&](int buf, int ks) {
#pragma unroll
    for (int i = 0; i < 4; ++i) {
      int base = i * 512 + w * 64;
      int rl   = base >> 8;                    // uniform per (i, wave)
      int rem  = (base & 255) + lane;
      const short* src = xw32 + ((size_t)(rl * 256 + kc * 8 + ks)) * 2048 + rem * 8;
      gll16(src, &bpanel[buf][(size_t)base * 8]);
    }
  };

  u32x4 Fa, Fb, Ea, Eb;                        // single raw slot (depth 1)
  struct Cv { u32x4 av; unsigned o0, o1; } C;
  auto ldraw = [&](int ks) {
    Fa = *(const u32x4*)(apf + ks * 16);
    Fb = *(const u32x4*)(apf + ks * 16 + 4);
    Ea = *(const u32x4*)(epf + ks * 16);
    Eb = *(const u32x4*)(epf + ks * 16 + 4);
  };
  auto conv = [&]() {
    C.av[0] = u2bf2(Fa[0], Fa[1]); C.av[1] = u2bf2(Fa[2], Fa[3]);
    C.av[2] = u2bf2(Fb[0], Fb[1]); C.av[3] = u2bf2(Fb[2], Fb[3]);
    unsigned o0 = 0, o1 = 0;
#pragma unroll
    for (int j = 0; j < 4; ++j) o0 |= (1u << (Ea[j] & 7u)) << (8 * j);
#pragma unroll
    for (int j = 0; j < 4; ++j) o1 |= (1u << (Eb[j] & 7u)) << (8 * j);
    C.o0 = o0; C.o1 = o1;
  };

  // prologue: stage panel0, load raw ks0
  stage(0, 0);
  ldraw(0);
  __syncthreads();                              // panel0 + raw0 complete

  int buf = 0;
#pragma unroll
  for (int ks = 0; ks < 8; ++ks) {
    if (ks < 7)
      stage(buf ^ 1, ks + 1);                   // async B for next phase FIRST
    conv();                                     // raw slot holds ks
    if (ks < 7)
      ldraw(ks + 1);                            // refill raw slot
    u32x4 av = C.av;
    unsigned o0 = C.o0, o1 = C.o1;

    __builtin_amdgcn_s_setprio(1);
#pragma unroll
    for (int r = 0; r < 8; ++r) {
      unsigned q0 = (o0 >> r) & 0x01010101u;
      unsigned q1 = (o1 >> r) & 0x01010101u;
      unsigned m0 = pairmask(q0, 0x01010000u);
      unsigned m1 = pairmask(q0, 0x03030202u);
      unsigned m2 = pairmask(q1, 0x01010000u);
      unsigned m3 = pairmask(q1, 0x03030202u);
      u32x4 mv;
      mv[0] = av[0] & m0; mv[1] = av[1] & m1;
      mv[2] = av[2] & m2; mv[3] = av[3] & m3;
      s16x8 mf = __builtin_bit_cast(s16x8, mv);
#pragma unroll
      for (int ct = 0; ct < 4; ++ct) {
        s16x8 b = *(const s16x8*)&bpanel[buf][((r * 4 + ct) * 64 + lane) * 8];
        acc[ct] = mfma32(mf, b, acc[ct]);
      }
    }
    __builtin_amdgcn_s_setprio(0);
    if (ks < 7) __syncthreads();                // next panel + raw complete
    buf ^= 1;
  }

  // epilogue: bf16 partials, 8B lane-contiguous stores
  short* tile = partial + ((size_t)(kc * 16 + rowblk)) * 32768;
#pragma unroll
  for (int ct = 0; ct < 4; ++ct)
#pragma unroll
    for (int rq = 0; rq < 4; ++rq) {
      short v[4];
#pragma unroll
      for (int j = 0; j < 4; ++j) v[j] = f2bf(acc[ct][rq * 4 + j]);
      __builtin_nontemporal_store(
          *(s16x4*)v, (s16x4*)(tile + ((size_t)((w * 4 + ct) * 4 + rq) * 64 + lane) * 4));
    }
}

// ---------------------------------------------------------------------------
// K4: out = LN( hacc + sum_kc bf16-partial ) (+ReLU). One wave per 4-row
// quad. Inverse of agg32 store.
// ---------------------------------------------------------------------------
__global__ void reduce_ln32(const short* __restrict__ partial,
                            const float* __restrict__ hacc,
                            const float* __restrict__ gamma, const float* __restrict__ beta,
                            float* __restrict__ out, int relu) {
  int lane = threadIdx.x & 63;
  int g = blockIdx.x * 4 + (threadIdx.x >> 6);   // row-quad id, 0..1023
  int rowbase = g * 4;
  int rb   = rowbase >> 8;
  int w    = (rowbase >> 5) & 7;
  int rq   = (rowbase >> 3) & 3;
  int bit2 = (rowbase >> 2) & 1;
  int l31 = lane & 31;
  int ct0 = lane >> 5;
  int lsrc = l31 + 32 * bit2;
  int c0 = lane, c1 = lane + 64;

  f32x4 v0, v1;
#pragma unroll
  for (int j = 0; j < 4; ++j) {
    v0[j] = hacc[(size_t)(rowbase + j) * 128 + c0];
    v1[j] = hacc[(size_t)(rowbase + j) * 128 + c1];
  }
  size_t off0 = ((size_t)((w * 4 + ct0) * 4 + rq) * 64 + lsrc) * 4;
  size_t off1 = ((size_t)((w * 4 + ct0 + 2) * 4 + rq) * 64 + lsrc) * 4;
  for (int kc = 0; kc < 32; ++kc) {
    const short* tile = partial + ((size_t)(kc * 16 + rb)) * 32768;
    s16x4 p0 = *(const s16x4*)(tile + off0);
    s16x4 p1 = *(const s16x4*)(tile + off1);
#pragma unroll
    for (int j = 0; j < 4; ++j) { v0[j] += bf2f(p0[j]); v1[j] += bf2f(p1[j]); }
  }

  f32x4 s, sq;
#pragma unroll
  for (int j = 0; j < 4; ++j) {
    s[j]  = v0[j] + v1[j];
    sq[j] = v0[j] * v0[j] + v1[j] * v1[j];
  }
#pragma unroll
  for (int off = 32; off; off >>= 1) {
#pragma unroll
    for (int j = 0; j < 4; ++j) {
      s[j]  += __shfl_xor(s[j],  off);
      sq[j] += __shfl_xor(sq[j], off);
    }
  }
  float g0 = gamma[c0], g1 = gamma[c1], b0 = beta[c0], b1 = beta[c1];
#pragma unroll
  for (int j = 0; j < 4; ++j) {
    float mu  = s[j] * (1.f / 128.f);
    float var = sq[j] * (1.f / 128.f) - mu * mu;
    float inv = rsqrtf(var + 1e-5f);
    float y0 = (v0[j] - mu) * inv * g0 + b0;
    float y1 = (v1[j] - mu) * inv * g1 + b1;
    if (relu) { y0 = fmaxf(y0, 0.f); y1 = fmaxf(y1, 0.f); }
    out[(size_t)(rowbase + j) * 128 + c0] = y0;
    out[(size_t)(rowbase + j) * 128 + c1] = y1;
  }
}

// ---------------------------------------------------------------------------
// Fallback path (R9-proven): 16x16 agg from raw inputs with f32 partials.
// ---------------------------------------------------------------------------
__launch_bounds__(512, 4)
__global__ void agg_fb(const float* __restrict__ adj, const int* __restrict__ et,
                       const short* __restrict__ xwfrag, float* __restrict__ partial,
                       int msteps) {
  int tid = threadIdx.x;
  int w = tid >> 6, lane = tid & 63;
  int kc = blockIdx.x, rowblk = blockIdx.y;
  int l15 = lane & 15, l4 = lane >> 4;
  int row = rowblk * 128 + w * 16 + l15;

  f32x4 acc[8] = {};
  for (int ms = 0; ms < msteps; ++ms) {
    int gm = kc * msteps + ms;
    size_t rbase = (size_t)row * 4096 + gm * 32 + 8 * l4;
    f32x4 f0 = *(const f32x4*)(adj + rbase);
    f32x4 f1 = *(const f32x4*)(adj + rbase + 4);
    i32x4 e0 = *(const i32x4*)(et + rbase);
    i32x4 e1 = *(const i32x4*)(et + rbase + 4);
    s16x8 a, cd;
#pragma unroll
    for (int e = 0; e < 4; ++e) { a[e] = f2bf(f0[e]); cd[e] = (short)e0[e]; }
#pragma unroll
    for (int e = 0; e < 4; ++e) { a[4 + e] = f2bf(f1[e]); cd[4 + e] = (short)e1[e]; }
#pragma unroll
    for (int r = 0; r < 8; ++r) {
      const short* bp = xwfrag + ((size_t)(r * 128 + gm) * 8) * 512 + lane * 8;
      s16x8 mf;
#pragma unroll
      for (int e = 0; e < 8; ++e) mf[e] = (cd[e] == (short)r) ? a[e] : (short)0;
#pragma unroll
      for (int t = 0; t < 8; ++t) {
        s16x8 b = *(const s16x8*)(bp + t * 512);
        acc[t] = mfma16(mf, b, acc[t]);
      }
    }
  }
  float* tile = partial + ((size_t)kc * 32 + rowblk) * 16384;
#pragma unroll
  for (int t = 0; t < 8; ++t)
    __builtin_nontemporal_store(
        acc[t], (f32x4*)(tile + (size_t)((w * 8 + t) * 256 + lane * 4)));
}

__global__ void reduce_fb(const float* __restrict__ partial, int KC,
                          const float* __restrict__ hacc,
                          const float* __restrict__ gamma, const float* __restrict__ beta,
                          float* __restrict__ out, int relu) {
  int lane = threadIdx.x & 63;
  int g = blockIdx.x * 4 + (threadIdx.x >> 6);
  int rowblk = g >> 5;
  int q = g & 31;
  int wq  = q >> 2;
  int l4g = q & 3;
  int rowbase = rowblk * 128 + q * 4;
  int c0 = lane, c1 = lane + 64;
  int t0 = lane >> 4, li = lane & 15;
  f32x4 v0, v1;
#pragma unroll
  for (int j = 0; j < 4; ++j) {
    v0[j] = hacc[(size_t)(rowbase + j) * 128 + c0];
    v1[j] = hacc[(size_t)(rowbase + j) * 128 + c1];
  }
  size_t off0 = (size_t)((wq * 8 + t0) * 256) + (l4g * 16 + li) * 4;
  size_t off1 = (size_t)((wq * 8 + t0 + 4) * 256) + (l4g * 16 + li) * 4;
  for (int kc = 0; kc < KC; ++kc) {
    const float* tile = partial + ((size_t)kc * 32 + rowblk) * 16384;
    f32x4 p0 = *(const f32x4*)(tile + off0);
    f32x4 p1 = *(const f32x4*)(tile + off1);
#pragma unroll
    for (int j = 0; j < 4; ++j) { v0[j] += p0[j]; v1[j] += p1[j]; }
  }
  f32x4 s, sq;
#pragma unroll
  for (int j = 0; j < 4; ++j) {
    s[j]  = v0[j] + v1[j];
    sq[j] = v0[j] * v0[j] + v1[j] * v1[j];
  }
#pragma unroll
  for (int off = 32; off; off >>= 1) {
#pragma unroll
    for (int j = 0; j < 4; ++j) {
      s[j]  += __shfl_xor(s[j],  off);
      sq[j] += __shfl_xor(sq[j], off);
    }
  }
  float g0 = gamma[c0], g1 = gamma[c1], b0 = beta[c0], b1 = beta[c1];
#pragma unroll
  for (int j = 0; j < 4; ++j) {
    float mu  = s[j] * (1.f / 128.f);
    float var = sq[j] * (1.f / 128.f) - mu * mu;
    float inv = rsqrtf(var + 1e-5f);
    float y0 = (v0[j] - mu) * inv * g0 + b0;
    float y1 = (v1[j] - mu) * inv * g1 + b1;
    if (relu) { y0 = fmaxf(y0, 0.f); y1 = fmaxf(y1, 0.f); }
    out[(size_t)(rowbase + j) * 128 + c0] = y0;
    out[(size_t)(rowbase + j) * 128 + c1] = y1;
  }
}

// ---------------------------------------------------------------------------
extern "C" void kernel_launch(void* const* d_in, const int* in_sizes, int n_in,
                              void* d_out, int out_size, void* d_ws, size_t ws_size,
                              hipStream_t stream) {
  const float* x      = (const float*)d_in[0];
  const float* adj    = (const float*)d_in[1];
  const int*   et     = (const int*)d_in[2];
  const float* bases1 = (const float*)d_in[3];
  const float* wts1   = (const float*)d_in[4];
  const float* wself1 = (const float*)d_in[5];
  const float* bself1 = (const float*)d_in[6];
  const float* bases2 = (const float*)d_in[7];
  const float* wts2   = (const float*)d_in[8];
  const float* wself2 = (const float*)d_in[9];
  const float* bself2 = (const float*)d_in[10];
  const float* gamma1 = (const float*)d_in[11];
  const float* beta1  = (const float*)d_in[12];
  const float* gamma2 = (const float*)d_in[13];
  const float* beta2  = (const float*)d_in[14];

  char* ws = (char*)d_ws;
  const size_t BASE = 589824ull + 8388608ull + 2097152ull + 2097152ull; // 13,172,736
  short* wfrag  = (short*)(ws);
  short* xwfrag = (short*)(ws + 589824);
  float* hacc   = (float*)(ws + 589824 + 8388608);
  float* h1     = (float*)(ws + 589824 + 8388608 + 2097152);

  const size_t P16 = 33554432ull;                 // bf16 partials
  bool main_path = ws_size >= BASE + P16;         // 46.7 MB

  prep_w<<<144, 256, 0, stream>>>(bases1, wts1, wself1, bases2, wts2, wself2, wfrag);

  if (main_path) {
    short* partial16 = (short*)(ws + BASE);
    dim3 agrid(32, 16);
    // layer 1
    xw_gemm<1><<<288, 256, 0, stream>>>(x, wfrag, xwfrag, hacc, bself1);
    agg32<<<agrid, 512, 0, stream>>>(adj, et, xwfrag, partial16);
    reduce_ln32<<<256, 256, 0, stream>>>(partial16, hacc, gamma1, beta1, h1, 1);
    // layer 2
    xw_gemm<1><<<288, 256, 0, stream>>>(h1, wfrag + 147456, xwfrag, hacc, bself2);
    agg32<<<agrid, 512, 0, stream>>>(adj, et, xwfrag, partial16);
    reduce_ln32<<<256, 256, 0, stream>>>(partial16, hacc, gamma2, beta2, (float*)d_out, 0);
  } else {
    // fallback: f32 partials, raw-input 16x16 agg
    int KC = 0;
    const int utiers[5] = {16, 8, 4, 2, 1};
    for (int i = 0; i < 5 && !KC; ++i)
      if (ws_size >= BASE + (size_t)utiers[i] * 2097152ull) KC = utiers[i];
    if (!KC) KC = 1;
    float* partialf = (float*)(ws + BASE);
    int msteps = 128 / KC;
    dim3 agrid(KC, 32);

    xw_gemm<0><<<288, 256, 0, stream>>>(x, wfrag, xwfrag, hacc, bself1);
    agg_fb<<<agrid, 512, 0, stream>>>(adj, et, xwfrag, partialf, msteps);
    reduce_fb<<<256, 256, 0, stream>>>(partialf, KC, hacc, gamma1, beta1, h1, 1);

    xw_gemm<0><<<288, 256, 0, stream>>>(h1, wfrag + 147456, xwfrag, hacc, bself2);
    agg_fb<<<agrid, 512, 0, stream>>>(adj, et, xwfrag, partialf, msteps);
    reduce_fb<<<256, 256, 0, stream>>>(partialf, KC, hacc, gamma2, beta2, (float*)d_out, 0);
  }
}